// Round 1
// baseline (606.054 us; speedup 1.0000x reference)
//
#include <hip/hip_runtime.h>
#include <stdint.h>

typedef unsigned short u16;
typedef __attribute__((ext_vector_type(8))) short bf16x8;
typedef __attribute__((ext_vector_type(4))) float f32x4;

#define MFMA16(a, b, c) __builtin_amdgcn_mfma_f32_16x16x32_bf16(a, b, c, 0, 0, 0)

__device__ __forceinline__ u16 f2bf(float x) {
  union { float f; uint32_t u; } v; v.f = x;
  uint32_t r = (v.u + 0x7FFFu + ((v.u >> 16) & 1u)) >> 16;
  return (u16)r;
}
__device__ __forceinline__ float bf2f(u16 h) {
  union { uint32_t u; float f; } v; v.u = ((uint32_t)h) << 16; return v.f;
}
__device__ __forceinline__ void gll16(const void* g, void* s) {
  __builtin_amdgcn_global_load_lds((const __attribute__((address_space(1))) unsigned int*)g,
                                   (__attribute__((address_space(3))) unsigned int*)s, 16, 0, 0);
}

// ---------------- pack kernels ----------------

// grid (6000,1,3), block 256: fp32 -> bf16, 4 elems/thread
__global__ __launch_bounds__(256) void pack_x_kernel(const float* __restrict__ q,
                                                     const float* __restrict__ k,
                                                     const float* __restrict__ v,
                                                     u16* __restrict__ X) {
  const float* src = blockIdx.z == 0 ? q : (blockIdx.z == 1 ? k : v);
  u16* dst = X + (size_t)blockIdx.z * (6016UL * 1024UL);
  size_t idx = (size_t)blockIdx.x * 1024 + (size_t)threadIdx.x * 4;
  float4 f = *(const float4*)(src + idx);
  ushort4 o;
  o.x = f2bf(f.x); o.y = f2bf(f.y); o.z = f2bf(f.z); o.w = f2bf(f.w);
  *(ushort4*)(dst + idx) = o;
}

// 1 block: bias concat + pos_k -> bf16 padded to 144 rows
__global__ __launch_bounds__(256) void pack_misc_kernel(const float* __restrict__ bq,
                                                        const float* __restrict__ bk,
                                                        const float* __restrict__ bv,
                                                        const float* __restrict__ posk,
                                                        float* __restrict__ biascat,
                                                        u16* __restrict__ poskbf) {
  for (int i = threadIdx.x; i < 1024; i += 256) {
    biascat[i] = bq[i]; biascat[1024 + i] = bk[i]; biascat[2048 + i] = bv[i];
  }
  for (int i = threadIdx.x; i < 144 * 64; i += 256) {
    int r = i >> 6;
    poskbf[i] = (r < 129) ? f2bf(posk[i]) : (u16)0;
  }
}

// grid (16,16,3): Wt[z][(n*64+d)*1024 + h] = W[z][n][h][d] (bf16)
__global__ __launch_bounds__(256) void pack_wqkv_kernel(const float* __restrict__ Wq,
                                                        const float* __restrict__ Wk,
                                                        const float* __restrict__ Wv,
                                                        u16* __restrict__ Wt) {
  __shared__ float tile[64][65];
  const float* W = blockIdx.z == 0 ? Wq : (blockIdx.z == 1 ? Wk : Wv);
  u16* dst = Wt + (size_t)blockIdx.z * (1024UL * 1024UL);
  const int n = blockIdx.y, h0 = blockIdx.x * 64;
  const int r = threadIdx.x >> 2, c0 = (threadIdx.x & 3) * 16;
  const float* src = W + (size_t)n * 65536 + (size_t)(h0 + r) * 64 + c0;
#pragma unroll
  for (int j = 0; j < 16; j += 4) {
    float4 f = *(const float4*)(src + j);
    tile[r][c0 + j] = f.x; tile[r][c0 + j + 1] = f.y;
    tile[r][c0 + j + 2] = f.z; tile[r][c0 + j + 3] = f.w;
  }
  __syncthreads();
  u16* outp = dst + (size_t)(n * 64 + r) * 1024 + h0 + c0;
#pragma unroll
  for (int j = 0; j < 16; ++j) outp[j] = f2bf(tile[c0 + j][r]);
}

// grid (16,16): Wfct[o*1024 + i] = Wfc[i*1024 + o] (bf16)
__global__ __launch_bounds__(256) void pack_wfc_kernel(const float* __restrict__ Wfc,
                                                       u16* __restrict__ Wfct) {
  __shared__ float tile[64][65];
  const int i0 = blockIdx.x * 64, o0 = blockIdx.y * 64;
  const int r = threadIdx.x >> 2, c0 = (threadIdx.x & 3) * 16;
  const float* src = Wfc + (size_t)(i0 + r) * 1024 + o0 + c0;
#pragma unroll
  for (int j = 0; j < 16; j += 4) {
    float4 f = *(const float4*)(src + j);
    tile[r][c0 + j] = f.x; tile[r][c0 + j + 1] = f.y;
    tile[r][c0 + j + 2] = f.z; tile[r][c0 + j + 3] = f.w;
  }
  __syncthreads();
  u16* outp = Wfct + (size_t)(o0 + r) * 1024 + i0 + c0;
#pragma unroll
  for (int j = 0; j < 16; ++j) outp[j] = f2bf(tile[c0 + j][r]);
}

// ---------------- GEMM: C[m,n] = sum_k A[m,k]*Bt[n,k] (+bias), m97-style ----------------
// mode 0: out bf16 scattered to qkv[z][b][h][s][d], scale 0.125 for z==0
// mode 1: out fp32 to outF[m*1024+n]
__global__ __launch_bounds__(256) void gemm_bt_kernel(
    const u16* __restrict__ Abase, long aStride,
    const u16* __restrict__ Bbase, long bStride,
    const float* __restrict__ biasBase, long biasStride,
    u16* __restrict__ outBF, float* __restrict__ outF, int mode) {
  const int z = blockIdx.z;
  const u16* A = Abase + (size_t)z * aStride;
  const u16* Bt = Bbase + (size_t)z * bStride;
  const float* bias = biasBase + (size_t)z * biasStride;
  __shared__ u16 As[128 * 32];
  __shared__ u16 Bs[128 * 32];
  const int tid = threadIdx.x, w = tid >> 6, lane = tid & 63;
  const int quad = lane >> 4, l16 = lane & 15;
  const int wm = w >> 1, wn = w & 1;
  const int m0 = blockIdx.y * 128, n0 = blockIdx.x * 128;
  const int srow = w * 16 + (lane >> 2);
  const int scol = (lane & 3) * 8;
  const u16* gA0 = A + (size_t)(m0 + srow) * 1024 + scol;
  const u16* gA1 = gA0 + 64UL * 1024;
  const u16* gB0 = Bt + (size_t)(n0 + srow) * 1024 + scol;
  const u16* gB1 = gB0 + 64UL * 1024;
  u16* lA0 = As + (w * 16) * 32;
  u16* lA1 = As + (64 + w * 16) * 32;
  u16* lB0 = Bs + (w * 16) * 32;
  u16* lB1 = Bs + (64 + w * 16) * 32;

  f32x4 acc[4][4];
  const f32x4 zf = {0.f, 0.f, 0.f, 0.f};
#pragma unroll
  for (int a = 0; a < 4; ++a)
#pragma unroll
    for (int b = 0; b < 4; ++b) acc[a][b] = zf;

  for (int kt = 0; kt < 32; ++kt) {
    const int k0 = kt * 32;
    gll16(gA0 + k0, lA0);
    gll16(gA1 + k0, lA1);
    gll16(gB0 + k0, lB0);
    gll16(gB1 + k0, lB1);
    __syncthreads();
    bf16x8 af[4], bfr[4];
#pragma unroll
    for (int f = 0; f < 4; ++f) {
      af[f]  = *(const bf16x8*)(As + (wm * 64 + f * 16 + l16) * 32 + quad * 8);
      bfr[f] = *(const bf16x8*)(Bs + (wn * 64 + f * 16 + l16) * 32 + quad * 8);
    }
#pragma unroll
    for (int fm = 0; fm < 4; ++fm)
#pragma unroll
      for (int fn = 0; fn < 4; ++fn)
        acc[fm][fn] = MFMA16(af[fm], bfr[fn], acc[fm][fn]);
    __syncthreads();
  }

  if (mode == 0) {
    const float scale = (z == 0) ? 0.125f : 1.0f;
    u16* out = outBF + (size_t)z * (4UL * 16 * 1536 * 64);
#pragma unroll
    for (int fm = 0; fm < 4; ++fm) {
#pragma unroll
      for (int i = 0; i < 4; ++i) {
        const int m = m0 + wm * 64 + fm * 16 + quad * 4 + i;
        if (m >= 6000) continue;
        const int bb = m / 1500;
        const int s = m - bb * 1500;
#pragma unroll
        for (int fn = 0; fn < 4; ++fn) {
          const int n = n0 + wn * 64 + fn * 16 + l16;
          const float vv = (acc[fm][fn][i] + bias[n]) * scale;
          const int h = n >> 6, d = n & 63;
          out[((size_t)(bb * 16 + h) * 1536 + s) * 64 + d] = f2bf(vv);
        }
      }
    }
  } else {
#pragma unroll
    for (int fm = 0; fm < 4; ++fm) {
#pragma unroll
      for (int i = 0; i < 4; ++i) {
        const int m = m0 + wm * 64 + fm * 16 + quad * 4 + i;
        if (m >= 6000) continue;
#pragma unroll
        for (int fn = 0; fn < 4; ++fn) {
          const int n = n0 + wn * 64 + fn * 16 + l16;
          outF[(size_t)m * 1024 + n] = acc[fm][fn][i] + bias[n];
        }
      }
    }
  }
}

// ---------------- fused attention ----------------
// grid (24, 16, 4), block 256 (4 waves); wave w owns q rows [q0+w*16, q0+w*16+16)
__global__ __launch_bounds__(256) void attn_kernel(const u16* __restrict__ qkv,
                                                   const u16* __restrict__ poskbf,
                                                   const float* __restrict__ posv,
                                                   u16* __restrict__ hidden) {
  const size_t ZS = 4UL * 16 * 1536 * 64;
  __shared__ u16 qp_s[64 * 144];      // bf16 qp[q][r]; reused as posvT[64][136] in epilogue
  __shared__ float pb_s[64 * 128];    // in-band rel-v histogram
  __shared__ u16 vt_s[64 * 40];       // V^T tile [d][k], pitch 40
  __shared__ u16 p_s[4][16 * 32];     // per-wave P tile [q][k], pitch 32

  const int tid = threadIdx.x;
  const int w = tid >> 6, lane = tid & 63, quad = lane >> 4, l16 = lane & 15;
  const int q0 = blockIdx.x * 64;
  const int head = blockIdx.y, b = blockIdx.z;
  const size_t sb = (size_t)(b * 16 + head) * (1536UL * 64UL);
  const u16* Qp = qkv + sb;
  const u16* Kp = qkv + ZS + sb;
  const u16* Vp = qkv + 2 * ZS + sb;

  for (int i = tid; i < 64 * 128; i += 256) pb_s[i] = 0.f;

  bf16x8 qA0, qA1;
  {
    const u16* qr = Qp + (size_t)(q0 + w * 16 + l16) * 64 + quad * 8;
    qA0 = *(const bf16x8*)qr;
    qA1 = *(const bf16x8*)(qr + 32);
  }
  // qp[q][r] = qs . pos_k[r]  via MFMA (N padded to 144)
#pragma unroll
  for (int nf = 0; nf < 9; ++nf) {
    const u16* bp = poskbf + (nf * 16 + l16) * 64 + quad * 8;
    bf16x8 b0 = *(const bf16x8*)bp;
    bf16x8 b1 = *(const bf16x8*)(bp + 32);
    f32x4 c = {0.f, 0.f, 0.f, 0.f};
    c = MFMA16(qA0, b0, c);
    c = MFMA16(qA1, b1, c);
#pragma unroll
    for (int i = 0; i < 4; ++i)
      qp_s[(w * 16 + quad * 4 + i) * 144 + nf * 16 + l16] = f2bf(c[i]);
  }
  __syncthreads();

  f32x4 accf[4];
  const f32x4 zf = {0.f, 0.f, 0.f, 0.f};
#pragma unroll
  for (int dc = 0; dc < 4; ++dc) accf[dc] = zf;
  float lpart[4] = {0.f, 0.f, 0.f, 0.f};
  float clow[4] = {0.f, 0.f, 0.f, 0.f};
  float chigh[4] = {0.f, 0.f, 0.f, 0.f};

  for (int it = 0; it < 47; ++it) {
    const int k0 = it * 32;
    bf16x8 vreg = *(const bf16x8*)(Vp + (size_t)(k0 + (tid >> 3)) * 64 + (tid & 7) * 8);

#pragma unroll
    for (int cg = 0; cg < 2; ++cg) {
      const int kc = k0 + cg * 16;
      const u16* kr = Kp + (size_t)(kc + l16) * 64 + quad * 8;
      bf16x8 kb0 = *(const bf16x8*)kr;
      bf16x8 kb1 = *(const bf16x8*)(kr + 32);
      f32x4 c = {0.f, 0.f, 0.f, 0.f};
      c = MFMA16(qA0, kb0, c);
      c = MFMA16(qA1, kb1, c);
      const int kg = kc + l16;
      const bool kvalid = (kg < 1500);
#pragma unroll
      for (int i = 0; i < 4; ++i) {
        const int ql = w * 16 + quad * 4 + i;   // block-local q row
        const int qg = q0 + ql;                 // global q index
        int delta = kg - qg;
        delta = delta < -64 ? -64 : (delta > 64 ? 64 : delta);
        delta += 64;
        const float sbias = bf2f(qp_s[ql * 144 + delta]);
        const float p = kvalid ? __expf(c[i] + sbias - 8.0f) : 0.0f;
        lpart[i] += p;
        if (delta == 0)        clow[i] += p;
        else if (delta == 128) chigh[i] += p;
        else                   atomicAdd(&pb_s[ql * 128 + delta], p);
        p_s[w][(quad * 4 + i) * 32 + cg * 16 + l16] = f2bf(p);
      }
    }
    __syncthreads();   // previous vt readers done
    {
      const int kl = tid >> 3, db = (tid & 7) * 8;
#pragma unroll
      for (int j = 0; j < 8; ++j) vt_s[(db + j) * 40 + kl] = (u16)vreg[j];
    }
    __syncthreads();   // vt ready
    bf16x8 pa = *(const bf16x8*)&p_s[w][l16 * 32 + quad * 8];
#pragma unroll
    for (int dc = 0; dc < 4; ++dc) {
      bf16x8 vb = *(const bf16x8*)&vt_s[(dc * 16 + l16) * 40 + quad * 8];
      accf[dc] = MFMA16(pa, vb, accf[dc]);
    }
  }
  __syncthreads();  // pb atomics done; qp no longer needed

  // stage pos_v^T bf16 (r 0..127) into qp_s region, pitch 136
  for (int i = tid; i < 64 * 128; i += 256) {
    const int d = i & 63, r = i >> 6;
    qp_s[d * 136 + r] = f2bf(posv[(size_t)r * 64 + d]);
  }
  __syncthreads();

  // o2 = pb[16x128] @ pos_v[128x64] via MFMA
  f32x4 o2[4];
#pragma unroll
  for (int dc = 0; dc < 4; ++dc) o2[dc] = zf;
#pragma unroll
  for (int kk = 0; kk < 4; ++kk) {
    const float* prow = &pb_s[(w * 16 + l16) * 128 + kk * 32 + quad * 8];
    bf16x8 a;
#pragma unroll
    for (int j = 0; j < 8; ++j) a[j] = (short)f2bf(prow[j]);
#pragma unroll
    for (int dc = 0; dc < 4; ++dc) {
      bf16x8 bv = *(const bf16x8*)&qp_s[(dc * 16 + l16) * 136 + kk * 32 + quad * 8];
      o2[dc] = MFMA16(a, bv, o2[dc]);
    }
  }

  // reduce softmax denominators + clamp tails across the 16 lanes of each quad
#pragma unroll
  for (int msk = 1; msk < 16; msk <<= 1) {
#pragma unroll
    for (int i = 0; i < 4; ++i) {
      lpart[i] += __shfl_xor(lpart[i], msk);
      clow[i]  += __shfl_xor(clow[i], msk);
      chigh[i] += __shfl_xor(chigh[i], msk);
    }
  }

#pragma unroll
  for (int i = 0; i < 4; ++i) {
    const int qg = q0 + w * 16 + quad * 4 + i;
    if (qg >= 1500) continue;
    const float linv = 1.0f / lpart[i];
#pragma unroll
    for (int dc = 0; dc < 4; ++dc) {
      const int d = dc * 16 + l16;
      const float val = accf[dc][i] + o2[dc][i] + clow[i] * posv[d] + chigh[i] * posv[128 * 64 + d];
      hidden[((size_t)(b * 1500 + qg)) * 1024 + head * 64 + d] = f2bf(val * linv);
    }
  }
}

// ---------------- launcher ----------------
extern "C" void kernel_launch(void* const* d_in, const int* in_sizes, int n_in,
                              void* d_out, int out_size, void* d_ws, size_t ws_size,
                              hipStream_t stream) {
  const float* query = (const float*)d_in[0];
  const float* key   = (const float*)d_in[1];
  const float* value = (const float*)d_in[2];
  const float* Wq = (const float*)d_in[3];
  const float* bq = (const float*)d_in[4];
  const float* Wk = (const float*)d_in[5];
  const float* bk = (const float*)d_in[6];
  const float* Wv = (const float*)d_in[7];
  const float* bv = (const float*)d_in[8];
  const float* posk = (const float*)d_in[9];
  const float* posv = (const float*)d_in[10];
  const float* Wfc = (const float*)d_in[11];
  const float* bfc = (const float*)d_in[12];
  float* out = (float*)d_out;

  char* p = (char*)d_ws;
  u16* X = (u16*)p;        p += 3UL * 6016 * 1024 * 2;   // Xq,Xk,Xv (M padded to 6016)
  u16* Wt = (u16*)p;       p += 3UL * 1024 * 1024 * 2;   // Wq_t,Wk_t,Wv_t
  u16* Wfct = (u16*)p;     p += 1024UL * 1024 * 2;
  u16* poskbf = (u16*)p;   p += 144UL * 64 * 2;
  float* biascat = (float*)p; p += 3UL * 1024 * 4;
  u16* qkv = (u16*)p;      p += 3UL * 4 * 16 * 1536 * 64 * 2;  // q,k,v [B*NH][1536][64]
  u16* hidden = X;  // alias: X is dead after QKV GEMM

  pack_x_kernel<<<dim3(6000, 1, 3), 256, 0, stream>>>(query, key, value, X);
  pack_misc_kernel<<<dim3(1), 256, 0, stream>>>(bq, bk, bv, posk, biascat, poskbf);
  pack_wqkv_kernel<<<dim3(16, 16, 3), 256, 0, stream>>>(Wq, Wk, Wv, Wt);
  pack_wfc_kernel<<<dim3(16, 16), 256, 0, stream>>>(Wfc, Wfct);

  gemm_bt_kernel<<<dim3(8, 47, 3), 256, 0, stream>>>(
      X, 6016L * 1024, Wt, 1024L * 1024, biascat, 1024L, qkv, nullptr, 0);

  attn_kernel<<<dim3(24, 16, 4), 256, 0, stream>>>(qkv, poskbf, posv, hidden);

  gemm_bt_kernel<<<dim3(8, 47, 1), 256, 0, stream>>>(
      hidden, 0L, Wfct, 0L, bfc, 0L, nullptr, out, 1);
}

// Round 3
// 546.051 us; speedup vs baseline: 1.1099x; 1.1099x over previous
//
#include <hip/hip_runtime.h>
#include <stdint.h>

typedef unsigned short u16;
typedef __attribute__((ext_vector_type(8))) short bf16x8;
typedef __attribute__((ext_vector_type(4))) float f32x4;

#define MFMA16(a, b, c) __builtin_amdgcn_mfma_f32_16x16x32_bf16(a, b, c, 0, 0, 0)

template <int N> struct IC { static constexpr int value = N; };

__device__ __forceinline__ u16 f2bf(float x) {
  union { float f; uint32_t u; } v; v.f = x;
  uint32_t r = (v.u + 0x7FFFu + ((v.u >> 16) & 1u)) >> 16;
  return (u16)r;
}
__device__ __forceinline__ float bf2f(u16 h) {
  union { uint32_t u; float f; } v; v.u = ((uint32_t)h) << 16; return v.f;
}
__device__ __forceinline__ void gll16(const void* g, void* s) {
  __builtin_amdgcn_global_load_lds((const __attribute__((address_space(1))) unsigned int*)g,
                                   (__attribute__((address_space(3))) unsigned int*)s, 16, 0, 0);
}

// ---------------- pack kernels ----------------

// grid (6000,1,3), block 256: fp32 -> bf16, 4 elems/thread
__global__ __launch_bounds__(256) void pack_x_kernel(const float* __restrict__ q,
                                                     const float* __restrict__ k,
                                                     const float* __restrict__ v,
                                                     u16* __restrict__ X) {
  const float* src = blockIdx.z == 0 ? q : (blockIdx.z == 1 ? k : v);
  u16* dst = X + (size_t)blockIdx.z * (6016UL * 1024UL);
  size_t idx = (size_t)blockIdx.x * 1024 + (size_t)threadIdx.x * 4;
  float4 f = *(const float4*)(src + idx);
  ushort4 o;
  o.x = f2bf(f.x); o.y = f2bf(f.y); o.z = f2bf(f.z); o.w = f2bf(f.w);
  *(ushort4*)(dst + idx) = o;
}

// 1 block: bias concat + pos_k bf16 (padded 144 rows) + pos_v^T bf16 (64 x 136)
__global__ __launch_bounds__(256) void pack_misc_kernel(const float* __restrict__ bq,
                                                        const float* __restrict__ bk,
                                                        const float* __restrict__ bv,
                                                        const float* __restrict__ posk,
                                                        const float* __restrict__ posv,
                                                        float* __restrict__ biascat,
                                                        u16* __restrict__ poskbf,
                                                        u16* __restrict__ posvT) {
  for (int i = threadIdx.x; i < 1024; i += 256) {
    biascat[i] = bq[i]; biascat[1024 + i] = bk[i]; biascat[2048 + i] = bv[i];
  }
  for (int i = threadIdx.x; i < 144 * 64; i += 256) {
    int r = i >> 6;
    poskbf[i] = (r < 129) ? f2bf(posk[i]) : (u16)0;
  }
  {
    const int d = threadIdx.x & 63, rr = threadIdx.x >> 6;
#pragma unroll
    for (int j = 0; j < 34; ++j) {
      const int r = rr * 34 + j;
      posvT[d * 136 + r] = (r < 129) ? f2bf(posv[(size_t)r * 64 + d]) : (u16)0;
    }
  }
}

// grid (16,16,3): Wt[z][(n*64+d)*1024 + h] = W[z][n][h][d] (bf16)
__global__ __launch_bounds__(256) void pack_wqkv_kernel(const float* __restrict__ Wq,
                                                        const float* __restrict__ Wk,
                                                        const float* __restrict__ Wv,
                                                        u16* __restrict__ Wt) {
  __shared__ float tile[64][65];
  const float* W = blockIdx.z == 0 ? Wq : (blockIdx.z == 1 ? Wk : Wv);
  u16* dst = Wt + (size_t)blockIdx.z * (1024UL * 1024UL);
  const int n = blockIdx.y, h0 = blockIdx.x * 64;
  const int r = threadIdx.x >> 2, c0 = (threadIdx.x & 3) * 16;
  const float* src = W + (size_t)n * 65536 + (size_t)(h0 + r) * 64 + c0;
#pragma unroll
  for (int j = 0; j < 16; j += 4) {
    float4 f = *(const float4*)(src + j);
    tile[r][c0 + j] = f.x; tile[r][c0 + j + 1] = f.y;
    tile[r][c0 + j + 2] = f.z; tile[r][c0 + j + 3] = f.w;
  }
  __syncthreads();
  u16* outp = dst + (size_t)(n * 64 + r) * 1024 + h0 + c0;
#pragma unroll
  for (int j = 0; j < 16; ++j) outp[j] = f2bf(tile[c0 + j][r]);
}

// grid (16,16): Wfct[o*1024 + i] = Wfc[i*1024 + o] (bf16)
__global__ __launch_bounds__(256) void pack_wfc_kernel(const float* __restrict__ Wfc,
                                                       u16* __restrict__ Wfct) {
  __shared__ float tile[64][65];
  const int i0 = blockIdx.x * 64, o0 = blockIdx.y * 64;
  const int r = threadIdx.x >> 2, c0 = (threadIdx.x & 3) * 16;
  const float* src = Wfc + (size_t)(i0 + r) * 1024 + o0 + c0;
#pragma unroll
  for (int j = 0; j < 16; j += 4) {
    float4 f = *(const float4*)(src + j);
    tile[r][c0 + j] = f.x; tile[r][c0 + j + 1] = f.y;
    tile[r][c0 + j + 2] = f.z; tile[r][c0 + j + 3] = f.w;
  }
  __syncthreads();
  u16* outp = Wfct + (size_t)(o0 + r) * 1024 + i0 + c0;
#pragma unroll
  for (int j = 0; j < 16; ++j) outp[j] = f2bf(tile[c0 + j][r]);
}

// grid (24,64): transpose V [bh][1536][64] -> Vt [bh][64][1536]
// 256 thr x 16 u16 = 4096 elems = full 64x64 tile. BUGFIX r2: stage BOTH
// uint4 halves (uint4 = 8 u16, stride is 16 u16) — r2 left half the LDS
// tile uninitialized -> NaN bf16 patterns in Vt.
__global__ __launch_bounds__(256) void vtrans_kernel(const u16* __restrict__ qkv,
                                                     u16* __restrict__ Vt) {
  const size_t ZS = 4UL * 16 * 1536 * 64;
  __shared__ u16 t[64][72];
  const int bh = blockIdx.y, s0 = blockIdx.x * 64;
  const u16* src = qkv + 2 * ZS + (size_t)bh * (1536UL * 64UL) + (size_t)s0 * 64;
  const int r = threadIdx.x >> 2, c0 = (threadIdx.x & 3) * 16;
  *(uint4*)&t[r][c0]     = *(const uint4*)(src + (size_t)r * 64 + c0);
  *(uint4*)&t[r][c0 + 8] = *(const uint4*)(src + (size_t)r * 64 + c0 + 8);
  __syncthreads();
  uint4 a, bvec;
  uint tmp[8];
#pragma unroll
  for (int j = 0; j < 8; ++j)
    tmp[j] = (uint)t[c0 + 2 * j][r] | ((uint)t[c0 + 2 * j + 1][r] << 16);
  a.x = tmp[0]; a.y = tmp[1]; a.z = tmp[2]; a.w = tmp[3];
  bvec.x = tmp[4]; bvec.y = tmp[5]; bvec.z = tmp[6]; bvec.w = tmp[7];
  u16* dst = Vt + (size_t)(bh * 64 + r) * 1536 + s0 + c0;
  *(uint4*)dst = a;
  *(uint4*)(dst + 8) = bvec;
}

// ---------------- GEMM: C[m,n] = sum_k A[m,k]*Bt[n,k] (+bias), m97-style ----------------
__global__ __launch_bounds__(256) void gemm_bt_kernel(
    const u16* __restrict__ Abase, long aStride,
    const u16* __restrict__ Bbase, long bStride,
    const float* __restrict__ biasBase, long biasStride,
    u16* __restrict__ outBF, float* __restrict__ outF, int mode) {
  const int z = blockIdx.z;
  const u16* A = Abase + (size_t)z * aStride;
  const u16* Bt = Bbase + (size_t)z * bStride;
  const float* bias = biasBase + (size_t)z * biasStride;
  __shared__ u16 As[128 * 32];
  __shared__ u16 Bs[128 * 32];
  const int tid = threadIdx.x, w = tid >> 6, lane = tid & 63;
  const int quad = lane >> 4, l16 = lane & 15;
  const int wm = w >> 1, wn = w & 1;
  const int m0 = blockIdx.y * 128, n0 = blockIdx.x * 128;
  const int srow = w * 16 + (lane >> 2);
  const int scol = (lane & 3) * 8;
  const u16* gA0 = A + (size_t)(m0 + srow) * 1024 + scol;
  const u16* gA1 = gA0 + 64UL * 1024;
  const u16* gB0 = Bt + (size_t)(n0 + srow) * 1024 + scol;
  const u16* gB1 = gB0 + 64UL * 1024;
  u16* lA0 = As + (w * 16) * 32;
  u16* lA1 = As + (64 + w * 16) * 32;
  u16* lB0 = Bs + (w * 16) * 32;
  u16* lB1 = Bs + (64 + w * 16) * 32;

  f32x4 acc[4][4];
  const f32x4 zf = {0.f, 0.f, 0.f, 0.f};
#pragma unroll
  for (int a = 0; a < 4; ++a)
#pragma unroll
    for (int b = 0; b < 4; ++b) acc[a][b] = zf;

  for (int kt = 0; kt < 32; ++kt) {
    const int k0 = kt * 32;
    gll16(gA0 + k0, lA0);
    gll16(gA1 + k0, lA1);
    gll16(gB0 + k0, lB0);
    gll16(gB1 + k0, lB1);
    __syncthreads();
    bf16x8 af[4], bfr[4];
#pragma unroll
    for (int f = 0; f < 4; ++f) {
      af[f]  = *(const bf16x8*)(As + (wm * 64 + f * 16 + l16) * 32 + quad * 8);
      bfr[f] = *(const bf16x8*)(Bs + (wn * 64 + f * 16 + l16) * 32 + quad * 8);
    }
#pragma unroll
    for (int fm = 0; fm < 4; ++fm)
#pragma unroll
      for (int fn = 0; fn < 4; ++fn)
        acc[fm][fn] = MFMA16(af[fm], bfr[fn], acc[fm][fn]);
    __syncthreads();
  }

  if (mode == 0) {
    const float scale = (z == 0) ? 0.125f : 1.0f;
    u16* out = outBF + (size_t)z * (4UL * 16 * 1536 * 64);
#pragma unroll
    for (int fm = 0; fm < 4; ++fm) {
#pragma unroll
      for (int i = 0; i < 4; ++i) {
        const int m = m0 + wm * 64 + fm * 16 + quad * 4 + i;
        if (m >= 6000) continue;
        const int bb = m / 1500;
        const int s = m - bb * 1500;
#pragma unroll
        for (int fn = 0; fn < 4; ++fn) {
          const int n = n0 + wn * 64 + fn * 16 + l16;
          const float vv = (acc[fm][fn][i] + bias[n]) * scale;
          const int h = n >> 6, d = n & 63;
          out[((size_t)(bb * 16 + h) * 1536 + s) * 64 + d] = f2bf(vv);
        }
      }
    }
  } else {
#pragma unroll
    for (int fm = 0; fm < 4; ++fm) {
#pragma unroll
      for (int i = 0; i < 4; ++i) {
        const int m = m0 + wm * 64 + fm * 16 + quad * 4 + i;
        if (m >= 6000) continue;
#pragma unroll
        for (int fn = 0; fn < 4; ++fn) {
          const int n = n0 + wn * 64 + fn * 16 + l16;
          outF[(size_t)m * 1024 + n] = acc[fm][fn][i] + bias[n];
        }
      }
    }
  }
}

// ---------------- fused attention v2 ----------------
// grid (24, 16, 4), block 256 = 4 independent waves; wave w owns q rows [q0+w*16, +16)
// S^T = K.Q^T MFMA layout: lane holds (k = kc+cg*16+quad*4+i, q = qw0+l16)
__global__ __launch_bounds__(256, 4) void attn_kernel(const u16* __restrict__ qkv,
                                                      const u16* __restrict__ Vt,
                                                      const u16* __restrict__ poskbf,
                                                      const u16* __restrict__ posvT,
                                                      const float* __restrict__ posv,
                                                      u16* __restrict__ hidden) {
  const size_t ZS = 4UL * 16 * 1536 * 64;
  __shared__ u16 qp_s[64 * 136];   // bf16 qp[q_local][r], per-wave 16-row slabs
  __shared__ u16 pb_s[64 * 136];   // bf16 in-band rel-v histogram [q_local][delta]
  __shared__ u16 p_s[4 * 16 * 40]; // per-wave P^ tile [q][k], pitch 40

  const int tid = threadIdx.x;
  const int w = tid >> 6, lane = tid & 63, quad = lane >> 4, l16 = lane & 15;
  const int q0 = blockIdx.x * 64, qw0 = q0 + w * 16;
  const int head = blockIdx.y, b = blockIdx.z;
  const int bh = b * 16 + head;
  const size_t sb = (size_t)bh * (1536UL * 64UL);
  const u16* Qp = qkv + sb;
  const u16* Kp = qkv + ZS + sb;
  const u16* Vrow = Vt + (size_t)bh * (64UL * 1536UL) + (size_t)l16 * 1536;
  u16* ps_w = p_s + w * 640;
  u16* qp_row = qp_s + (w * 16 + l16) * 136;
  u16* pb_row = pb_s + (w * 16 + l16) * 136;

  // zero own pb slab (wave-private)
  {
    uint* pz = (uint*)(pb_s + w * 16 * 136);
    for (int i = lane; i < 1088; i += 64) pz[i] = 0u;
  }

  // Q fragment (rows q = qw0 + l16)
  const u16* qptr = Qp + (size_t)(qw0 + l16) * 64 + quad * 8;
  const bf16x8 qB0 = *(const bf16x8*)qptr;
  const bf16x8 qB1 = *(const bf16x8*)(qptr + 32);

  // qp[q][r] = q . pos_k[r] via MFMA; C layout: row q_loc = quad*4+i, col r = l16
#pragma unroll
  for (int nf = 0; nf < 9; ++nf) {
    const u16* bp = poskbf + (size_t)(nf * 16 + l16) * 64 + quad * 8;
    bf16x8 b0 = *(const bf16x8*)bp;
    bf16x8 b1 = *(const bf16x8*)(bp + 32);
    f32x4 c = {0.f, 0.f, 0.f, 0.f};
    c = MFMA16(qB0, b0, c);
    c = MFMA16(qB1, b1, c);
    const int col = nf * 16 + l16;
    if (col < 136) {
#pragma unroll
      for (int i = 0; i < 4; ++i)
        qp_s[(w * 16 + quad * 4 + i) * 136 + col] = f2bf(c[i]);
    }
  }
  __syncthreads();

  const float L2E = 1.44269504f;
  const float M8 = -8.0f * L2E;
  const float eLow  = __builtin_fmaf(bf2f(qp_row[0]), L2E, M8);
  const float eHigh = __builtin_fmaf(bf2f(qp_row[128]), L2E, M8);

  f32x4 accf[4];
  const f32x4 zf = {0.f, 0.f, 0.f, 0.f};
#pragma unroll
  for (int dc = 0; dc < 4; ++dc) accf[dc] = zf;
  float sLow = 0.f, sHigh = 0.f, sDall = 0.f, sD0 = 0.f, sD128 = 0.f;

  auto run_tile = [&](int it, auto PH) {
    constexpr int PHASE = decltype(PH)::value;  // 0 low, 1 diag(masked), 2 high
    const int kc = it * 32;
    const u16* kptr = Kp + (size_t)(kc + l16) * 64 + quad * 8;
    bf16x8 ka[2][2];
    ka[0][0] = *(const bf16x8*)kptr;
    ka[0][1] = *(const bf16x8*)(kptr + 32);
    ka[1][0] = *(const bf16x8*)(kptr + 1024);
    ka[1][1] = *(const bf16x8*)(kptr + 1024 + 32);
    f32x4 cc[2];
#pragma unroll
    for (int cg = 0; cg < 2; ++cg) {
      cc[cg] = zf;
      cc[cg] = MFMA16(ka[cg][0], qB0, cc[cg]);
      cc[cg] = MFMA16(ka[cg][1], qB1, cc[cg]);
    }
    float pv[2][4];
#pragma unroll
    for (int cg = 0; cg < 2; ++cg) {
      if constexpr (PHASE == 0) {
#pragma unroll
        for (int i = 0; i < 4; ++i) {
          float p = __builtin_amdgcn_exp2f(__builtin_fmaf(cc[cg][i], L2E, eLow));
          sLow += p; pv[cg][i] = p;
        }
      } else if constexpr (PHASE == 2) {
#pragma unroll
        for (int i = 0; i < 4; ++i) {
          float p = __builtin_amdgcn_exp2f(__builtin_fmaf(cc[cg][i], L2E, eHigh));
          sHigh += p; pv[cg][i] = p;
        }
      } else {
        const int krow0 = kc + cg * 16 + quad * 4;
        const int dbase = krow0 + 64 - qw0 - l16;
#pragma unroll
        for (int i = 0; i < 4; ++i) {
          int delta = dbase + i;
          delta = delta < 0 ? 0 : (delta > 128 ? 128 : delta);
          const float t = cc[cg][i] + bf2f(qp_row[delta]);
          float p = __builtin_amdgcn_exp2f(__builtin_fmaf(t, L2E, M8));
          if (krow0 + i >= 1500) p = 0.f;
          sDall += p;
          sD0   += (delta == 0)   ? p : 0.f;
          sD128 += (delta == 128) ? p : 0.f;
          if ((delta != 0) & (delta != 128)) pb_row[delta] = f2bf(p);
          pv[cg][i] = p;
        }
      }
    }
    // P^T pack: store rows q=l16 of P (cols k) as 2x b64, read back as A-fragment
#pragma unroll
    for (int cg = 0; cg < 2; ++cg) {
      uint2 pk;
      pk.x = (uint)f2bf(pv[cg][0]) | ((uint)f2bf(pv[cg][1]) << 16);
      pk.y = (uint)f2bf(pv[cg][2]) | ((uint)f2bf(pv[cg][3]) << 16);
      *(uint2*)(ps_w + l16 * 40 + cg * 16 + quad * 4) = pk;
    }
    bf16x8 pa = *(const bf16x8*)(ps_w + l16 * 40 + quad * 8);
    const u16* vp = Vrow + kc + quad * 8;
#pragma unroll
    for (int dc = 0; dc < 4; ++dc) {
      bf16x8 vb = *(const bf16x8*)(vp + dc * 16 * 1536);
      accf[dc] = MFMA16(pa, vb, accf[dc]);
    }
  };

  const int itLowEnd = (qw0 >= 95) ? (((qw0 - 95) >> 5) + 1) : 0;
  const int itHigh0 = (qw0 + 110) >> 5;
  const int dEnd = itHigh0 < 46 ? itHigh0 : 46;

  for (int it = 0; it < itLowEnd; ++it) run_tile(it, IC<0>{});
  for (int it = itLowEnd; it < dEnd; ++it) run_tile(it, IC<1>{});
  for (int it = itHigh0; it < 46; ++it) run_tile(it, IC<2>{});
  run_tile(46, IC<1>{});

  // reduce softmax state over the 4 quads (q = l16 per lane)
  float lpart = sLow + sHigh + sDall;
  float clow = sLow + sD0;
  float chigh = sHigh + sD128;
#pragma unroll
  for (int m = 16; m <= 32; m <<= 1) {
    lpart += __shfl_xor(lpart, m);
    clow  += __shfl_xor(clow, m);
    chigh += __shfl_xor(chigh, m);
  }
  const float linv = 1.0f / lpart;
  float* red = (float*)ps_w;  // P tile dead; reuse per-wave region
  if (quad == 0) { red[l16] = linv; red[16 + l16] = clow; red[32 + l16] = chigh; }

  // o2 = pb[16x128] @ pos_v[128x64] via MFMA (A rows q=l16 from pb, B rows d from posvT)
  f32x4 o2[4];
#pragma unroll
  for (int dc = 0; dc < 4; ++dc) o2[dc] = zf;
  const u16* pbr = pb_s + (w * 16 + l16) * 136;
#pragma unroll
  for (int kk = 0; kk < 4; ++kk) {
    bf16x8 pa2 = *(const bf16x8*)(pbr + kk * 32 + quad * 8);
#pragma unroll
    for (int dc = 0; dc < 4; ++dc) {
      bf16x8 vb2 = *(const bf16x8*)(posvT + (size_t)(dc * 16 + l16) * 136 + kk * 32 + quad * 8);
      o2[dc] = MFMA16(pa2, vb2, o2[dc]);
    }
  }

#pragma unroll
  for (int dc = 0; dc < 4; ++dc) {
    const int d = dc * 16 + l16;
    const float pv0 = posv[d], pv1 = posv[128 * 64 + d];
#pragma unroll
    for (int i = 0; i < 4; ++i) {
      const int qg = qw0 + quad * 4 + i;
      if (qg < 1500) {
        const float li = red[quad * 4 + i];
        const float cl = red[16 + quad * 4 + i];
        const float ch = red[32 + quad * 4 + i];
        const float val = (accf[dc][i] + o2[dc][i] + cl * pv0 + ch * pv1) * li;
        hidden[((size_t)(b * 1500 + qg)) * 1024 + head * 64 + d] = f2bf(val);
      }
    }
  }
}

// ---------------- launcher ----------------
extern "C" void kernel_launch(void* const* d_in, const int* in_sizes, int n_in,
                              void* d_out, int out_size, void* d_ws, size_t ws_size,
                              hipStream_t stream) {
  const float* query = (const float*)d_in[0];
  const float* key   = (const float*)d_in[1];
  const float* value = (const float*)d_in[2];
  const float* Wq = (const float*)d_in[3];
  const float* bq = (const float*)d_in[4];
  const float* Wk = (const float*)d_in[5];
  const float* bk = (const float*)d_in[6];
  const float* Wv = (const float*)d_in[7];
  const float* bv = (const float*)d_in[8];
  const float* posk = (const float*)d_in[9];
  const float* posv = (const float*)d_in[10];
  const float* Wfc = (const float*)d_in[11];
  const float* bfc = (const float*)d_in[12];
  float* out = (float*)d_out;

  char* p = (char*)d_ws;
  u16* X = (u16*)p;        p += 3UL * 6016 * 1024 * 2;   // Xq,Xk,Xv (M padded to 6016)
  u16* Wt = (u16*)p;       p += 3UL * 1024 * 1024 * 2;   // Wq_t,Wk_t,Wv_t
  u16* Wfct = (u16*)p;     p += 1024UL * 1024 * 2;
  u16* poskbf = (u16*)p;   p += 144UL * 64 * 2;
  u16* posvT = (u16*)p;    p += 64UL * 136 * 2;
  float* biascat = (float*)p; p += 3UL * 1024 * 4;
  u16* qkv = (u16*)p;      p += 3UL * 4 * 16 * 1536 * 64 * 2;  // q,k,v [B*NH][1536][64]
  u16* hidden = X;                       // X[0 .. 6.14M elems) dead after QKV GEMM
  u16* Vt = X + 6291456;                 // aliases Xk/Xv region, dead after QKV GEMM

  pack_x_kernel<<<dim3(6000, 1, 3), 256, 0, stream>>>(query, key, value, X);
  pack_misc_kernel<<<dim3(1), 256, 0, stream>>>(bq, bk, bv, posk, posv, biascat, poskbf, posvT);
  pack_wqkv_kernel<<<dim3(16, 16, 3), 256, 0, stream>>>(Wq, Wk, Wv, Wt);
  pack_wfc_kernel<<<dim3(16, 16), 256, 0, stream>>>(Wfc, Wfct);

  gemm_bt_kernel<<<dim3(8, 47, 3), 256, 0, stream>>>(
      X, 6016L * 1024, Wt, 1024L * 1024, biascat, 1024L, qkv, nullptr, 0);

  vtrans_kernel<<<dim3(24, 64), 256, 0, stream>>>(qkv, Vt);

  attn_kernel<<<dim3(24, 16, 4), 256, 0, stream>>>(qkv, Vt, poskbf, posvT, posv, hidden);

  gemm_bt_kernel<<<dim3(8, 47, 1), 256, 0, stream>>>(
      hidden, 0L, Wfct, 0L, bfc, 0L, nullptr, out, 1);
}